// Round 1
// baseline (194.676 us; speedup 1.0000x reference)
//
#include <hip/hip_runtime.h>

#define LMBDA 0.001f
#define NS_SY 4     // NS iters for inv(sy): ||I-sy||~0.8 -> 0.8^16=0.028, lambda-damped
#define NS_G  5     // NS iters for inv(G1), Frobenius alpha (rho0~0.8 -> 8e-4)
#define NS_SX 5     // NS iters for inv(sx): enters lambda-damped R2/R4/T1
#define OUTER 3     // outer Richardson iters
#define LDP 68      // padded stride for row-chunk reads

// workspace layout (float offsets)
#define WS_A    0        // 64*256
#define WS_FY   16384    // 64*256
#define WS_G1   32768
#define WS_T1   36864
#define WS_R2   40960
#define WS_R4   45056
#define WS_GINV 49152
#define WS_C    53248
#define WS_FYAT 57344
#define WS_FLAGS 61440   // 16 ints: [0..7] per-gx gemm cnt (27); [8] G1-chunk cnt (4);
                         // [9] prep cnt (4); [10] gemm total (216)

#define FMA4(ar, xs, b) { ar[0]=fmaf((xs),(b).x,ar[0]); ar[1]=fmaf((xs),(b).y,ar[1]); \
                          ar[2]=fmaf((xs),(b).z,ar[2]); ar[3]=fmaf((xs),(b).w,ar[3]); }

// C-tile += A[4ti..][:] * B[:][4tj..]; all f4 (b128) LDS reads
template<int SA, int SB>
__device__ __forceinline__ void mm64(const float* __restrict__ A,
                                     const float* __restrict__ B,
                                     int ti, int tj, float a[4][4]) {
    #pragma unroll 4
    for (int k = 0; k < 64; k += 4) {
        float4 av0 = *(const float4*)&A[(4 * ti + 0) * SA + k];
        float4 av1 = *(const float4*)&A[(4 * ti + 1) * SA + k];
        float4 av2 = *(const float4*)&A[(4 * ti + 2) * SA + k];
        float4 av3 = *(const float4*)&A[(4 * ti + 3) * SA + k];
        float4 b0 = *(const float4*)&B[(k + 0) * SB + 4 * tj];
        float4 b1 = *(const float4*)&B[(k + 1) * SB + 4 * tj];
        float4 b2 = *(const float4*)&B[(k + 2) * SB + 4 * tj];
        float4 b3 = *(const float4*)&B[(k + 3) * SB + 4 * tj];
        FMA4(a[0], av0.x, b0); FMA4(a[0], av0.y, b1); FMA4(a[0], av0.z, b2); FMA4(a[0], av0.w, b3);
        FMA4(a[1], av1.x, b0); FMA4(a[1], av1.y, b1); FMA4(a[1], av1.z, b2); FMA4(a[1], av1.w, b3);
        FMA4(a[2], av2.x, b0); FMA4(a[2], av2.y, b1); FMA4(a[2], av2.z, b2); FMA4(a[2], av2.w, b3);
        FMA4(a[3], av3.x, b0); FMA4(a[3], av3.y, b1); FMA4(a[3], av3.z, b2); FMA4(a[3], av3.w, b3);
    }
}

// ---- Newton-Schulz: X <- X(2I - M X), X0 = alpha*I. sM,sX pad; sY flat ----
__device__ __forceinline__ void ns_invert(float* sM, float* sX, float* sY,
                                          int iters, int ti, int tj,
                                          int tid, float alpha)
{
    for (int idx = tid; idx < 4096; idx += 256) {
        int i = idx >> 6, j = idx & 63;
        sX[i * LDP + j] = (i == j) ? alpha : 0.f;
    }
    __syncthreads();
    for (int it = 0; it < iters; ++it) {
        float y[4][4];
        #pragma unroll
        for (int r = 0; r < 4; ++r)
            #pragma unroll
            for (int c = 0; c < 4; ++c) y[r][c] = 0.f;
        mm64<LDP, LDP>(sM, sX, ti, tj, y);          // Y = M*X
        #pragma unroll
        for (int r = 0; r < 4; ++r) {
            float4 v = {y[r][0], y[r][1], y[r][2], y[r][3]};
            *(float4*)&sY[(4 * ti + r) * 64 + 4 * tj] = v;
        }
        __syncthreads();
        float z[4][4];
        #pragma unroll
        for (int r = 0; r < 4; ++r)
            #pragma unroll
            for (int c = 0; c < 4; ++c) z[r][c] = 0.f;
        mm64<LDP, 64>(sX, sY, ti, tj, z);           // Z = X*Y
        __syncthreads();
        #pragma unroll
        for (int r = 0; r < 4; ++r) {
            float4 xv = *(const float4*)&sX[(4 * ti + r) * LDP + 4 * tj];
            xv.x = 2.f * xv.x - z[r][0];
            xv.y = 2.f * xv.y - z[r][1];
            xv.z = 2.f * xv.z - z[r][2];
            xv.w = 2.f * xv.w - z[r][3];
            *(float4*)&sX[(4 * ti + r) * LDP + 4 * tj] = xv;
        }
        __syncthreads();
    }
}

// ---- device-scope producer/consumer handoff ------------------------------
__device__ __forceinline__ void wait_ge(int* flag, int target, int tid) {
    if (tid == 0) {
        while (__hip_atomic_load(flag, __ATOMIC_ACQUIRE, __HIP_MEMORY_SCOPE_AGENT) < target)
            __builtin_amdgcn_s_sleep(2);
    }
    __syncthreads();
    __threadfence();   // acquire for all threads of the block
}

__device__ __forceinline__ void signal_one(int* flag, int tid) {
    __syncthreads();   // all block stores issued & drained (vmcnt(0) at barrier)
    __threadfence();   // device-scope release (L2 writeback)
    if (tid == 0)
        (void)__hip_atomic_fetch_add(flag, 1, __ATOMIC_RELEASE, __HIP_MEMORY_SCOPE_AGENT);
}

// ---------------- single fused kernel, 225 co-resident blocks -------------
// 0..215 : GEMM  A = tx@fx, Fy = ty@fy  (gx = bid&7 -> mat/m0, gy = bid>>3)
// 216..219: G1 chunk ch: partial A_ch A_ch^T -> atomicAdd WS_G1  (waits cnt[ch]==27)
// 220    : b0  sy chain (no deps)          221: b2 sx chain (no deps)
// 222    : b1' Frobenius + NS(G1) -> GINV  (waits G1 chunks)
// 223    : b3  FyAT = Fy A^T               (waits all 216 gemm blocks)
// 224    : k3  Richardson solve            (waits b0,b1',b2,b3)
__global__ __launch_bounds__(256, 1) void fused_fmnet(
    const float* __restrict__ fx, const float* __restrict__ fy,
    const float* __restrict__ ex, const float* __restrict__ ey,
    const float* __restrict__ tx, const float* __restrict__ ty,
    const float* __restrict__ sx, const float* __restrict__ sy,
    float* __restrict__ ws, float* __restrict__ out)
{
    extern __shared__ __align__(16) float lds[];
    int* flags = (int*)(ws + WS_FLAGS);
    const int tid = threadIdx.x;
    const int ti = tid >> 4, tj = tid & 15;
    const int bid = blockIdx.x;

    if (bid < 216) {
        // ---------------- GEMM part (old k1) ----------------
        float* sT = lds;            // sT[v][k]
        float* sF = lds + 4352;     // sF[v][m]
        const int gx = bid & 7, gy = bid >> 3;
        const int mat = gx >> 2;
        const int m0 = (gx & 3) << 6;
        const float* __restrict__ T = mat ? ty : tx;
        const float* __restrict__ F = mat ? fy : fx;
        float* __restrict__ Out = ws + (mat ? WS_FY : WS_A);

        float acc[4][4];
        #pragma unroll
        for (int r = 0; r < 4; ++r)
            #pragma unroll
            for (int c = 0; c < 4; ++c) acc[r][c] = 0.f;

        for (int sc = gy; sc * 64 < 5000; sc += 27) {
            const int v0 = sc << 6;
            int vlen = 5000 - v0; if (vlen > 64) vlen = 64;   // 64 or 8
            #pragma unroll
            for (int w = 0; w < 4; ++w) {
                const int fidx = tid + (w << 8);
                const int row = fidx >> 4, q = fidx & 15;
                const int vv = q << 2;
                if (vv < vlen) {   // sT[vv+i][row] = T[row, v0+vv+i]
                    float4 val = *(const float4*)(T + (size_t)row * 5000 + v0 + vv);
                    sT[(vv + 0) * LDP + row] = val.x;
                    sT[(vv + 1) * LDP + row] = val.y;
                    sT[(vv + 2) * LDP + row] = val.z;
                    sT[(vv + 3) * LDP + row] = val.w;
                }
                if (row < vlen) {  // sF[row][4q..] = F[v0+row, m0+4q..]
                    *(float4*)&sF[row * LDP + (q << 2)] =
                        *(const float4*)(F + (size_t)(v0 + row) * 256 + m0 + (q << 2));
                }
            }
            __syncthreads();
            for (int v = 0; v < vlen; ++v) {
                float4 av = *(const float4*)&sT[v * LDP + 4 * ti];
                float4 bv = *(const float4*)&sF[v * LDP + 4 * tj];
                FMA4(acc[0], av.x, bv); FMA4(acc[1], av.y, bv);
                FMA4(acc[2], av.z, bv); FMA4(acc[3], av.w, bv);
            }
            __syncthreads();
        }
        #pragma unroll
        for (int r = 0; r < 4; ++r)
            #pragma unroll
            for (int c = 0; c < 4; ++c)
                atomicAdd(&Out[(4 * ti + r) * 256 + m0 + 4 * tj + c], acc[r][c]);
        __syncthreads();
        __threadfence();
        if (tid == 0) {
            (void)__hip_atomic_fetch_add(&flags[gx], 1, __ATOMIC_RELEASE, __HIP_MEMORY_SCOPE_AGENT);
            (void)__hip_atomic_fetch_add(&flags[10], 1, __ATOMIC_RELEASE, __HIP_MEMORY_SCOPE_AGENT);
        }
    } else if (bid < 220) {
        // ---------------- G1 chunk: partial = A[:,64ch..] A[:,64ch..]^T ----
        const int ch = bid - 216;
        wait_ge(&flags[ch], 27, tid);
        float* sA = lds;             // pad
        for (int idx = tid; idx < 1024; idx += 256) {
            int i = idx >> 4, m4 = (idx & 15) << 2;
            *(float4*)&sA[i * LDP + m4] =
                *(const float4*)&ws[WS_A + i * 256 + (ch << 6) + m4];
        }
        __syncthreads();
        float a[4][4];
        #pragma unroll
        for (int r = 0; r < 4; ++r)
            #pragma unroll
            for (int c = 0; c < 4; ++c) a[r][c] = 0.f;
        for (int m = 0; m < 64; m += 4) {
            float4 av[4], bv[4];
            #pragma unroll
            for (int r = 0; r < 4; ++r) av[r] = *(const float4*)&sA[(4 * ti + r) * LDP + m];
            #pragma unroll
            for (int c = 0; c < 4; ++c) bv[c] = *(const float4*)&sA[(4 * tj + c) * LDP + m];
            #pragma unroll
            for (int r = 0; r < 4; ++r)
                #pragma unroll
                for (int c = 0; c < 4; ++c)
                    a[r][c] += av[r].x * bv[c].x + av[r].y * bv[c].y
                             + av[r].z * bv[c].z + av[r].w * bv[c].w;
        }
        #pragma unroll
        for (int r = 0; r < 4; ++r)
            #pragma unroll
            for (int c = 0; c < 4; ++c)
                atomicAdd(&ws[WS_G1 + (4 * ti + r) * 64 + 4 * tj + c], a[r][c]);
        __syncthreads();
        __threadfence();
        if (tid == 0)
            (void)__hip_atomic_fetch_add(&flags[8], 1, __ATOMIC_RELEASE, __HIP_MEMORY_SCOPE_AGENT);
    } else if (bid == 220) {
        // ---------------- b0: sy chain (no deps) ----------------
        float* sSy = lds;            // pad: sy, later Hinv
        float* sXx = lds + 4352;     // pad: NS X -> Sinv
        float* sYy = lds + 8704;     // flat: NS tmp
        float* sH  = lds + 12800;    // flat: H1
        float* sV  = lds + 16896;    // ey
        for (int idx = tid; idx < 1024; idx += 256) {
            int i = idx >> 4, j4 = (idx & 15) << 2;
            *(float4*)&sSy[i * LDP + j4] = *(const float4*)&sy[i * 64 + j4];
        }
        if (tid < 64) sV[tid] = ey[tid];
        __syncthreads();
        // H1 = sy^T sy
        {
            float h[4][4];
            #pragma unroll
            for (int r = 0; r < 4; ++r)
                #pragma unroll
                for (int c = 0; c < 4; ++c) h[r][c] = 0.f;
            for (int k = 0; k < 64; ++k) {
                float4 av = *(const float4*)&sSy[k * LDP + 4 * ti];
                float4 bv = *(const float4*)&sSy[k * LDP + 4 * tj];
                FMA4(h[0], av.x, bv); FMA4(h[1], av.y, bv);
                FMA4(h[2], av.z, bv); FMA4(h[3], av.w, bv);
            }
            #pragma unroll
            for (int r = 0; r < 4; ++r) {
                float4 v = {h[r][0], h[r][1], h[r][2], h[r][3]};
                *(float4*)&sH[(4 * ti + r) * 64 + 4 * tj] = v;
            }
        }
        __syncthreads();
        ns_invert(sSy, sXx, sYy, NS_SY, ti, tj, tid, 1.0f);   // Sinv
        // Hinv = Sinv Sinv^T -> overwrite sSy
        {
            float h[4][4];
            #pragma unroll
            for (int r = 0; r < 4; ++r)
                #pragma unroll
                for (int c = 0; c < 4; ++c) h[r][c] = 0.f;
            for (int m = 0; m < 64; m += 4) {
                float4 av[4], bv[4];
                #pragma unroll
                for (int r = 0; r < 4; ++r) av[r] = *(const float4*)&sXx[(4 * ti + r) * LDP + m];
                #pragma unroll
                for (int c = 0; c < 4; ++c) bv[c] = *(const float4*)&sXx[(4 * tj + c) * LDP + m];
                #pragma unroll
                for (int r = 0; r < 4; ++r)
                    #pragma unroll
                    for (int c = 0; c < 4; ++c)
                        h[r][c] += av[r].x * bv[c].x + av[r].y * bv[c].y
                                 + av[r].z * bv[c].z + av[r].w * bv[c].w;
            }
            __syncthreads();
            #pragma unroll
            for (int r = 0; r < 4; ++r) {
                float4 v = {h[r][0], h[r][1], h[r][2], h[r][3]};
                *(float4*)&sSy[(4 * ti + r) * LDP + 4 * tj] = v;
            }
        }
        __syncthreads();
        // C = Hinv * (D H1)
        {
            float a[4][4];
            #pragma unroll
            for (int r = 0; r < 4; ++r)
                #pragma unroll
                for (int c = 0; c < 4; ++c) a[r][c] = 0.f;
            #pragma unroll 4
            for (int k = 0; k < 64; k += 4) {
                float4 av[4];
                #pragma unroll
                for (int r = 0; r < 4; ++r) av[r] = *(const float4*)&sSy[(4 * ti + r) * LDP + k];
                #pragma unroll
                for (int q = 0; q < 4; ++q) {
                    float e = sV[k + q];
                    float4 bv = *(const float4*)&sH[(k + q) * 64 + 4 * tj];
                    bv.x *= e; bv.y *= e; bv.z *= e; bv.w *= e;
                    float xq[4] = {av[0].x, av[1].x, av[2].x, av[3].x};
                    if (q == 1) { xq[0]=av[0].y; xq[1]=av[1].y; xq[2]=av[2].y; xq[3]=av[3].y; }
                    if (q == 2) { xq[0]=av[0].z; xq[1]=av[1].z; xq[2]=av[2].z; xq[3]=av[3].z; }
                    if (q == 3) { xq[0]=av[0].w; xq[1]=av[1].w; xq[2]=av[2].w; xq[3]=av[3].w; }
                    #pragma unroll
                    for (int r = 0; r < 4; ++r) FMA4(a[r], xq[r], bv);
                }
            }
            #pragma unroll
            for (int r = 0; r < 4; ++r) {
                float4 v = {a[r][0], a[r][1], a[r][2], a[r][3]};
                *(float4*)&ws[WS_C + (4 * ti + r) * 64 + 4 * tj] = v;
            }
        }
        signal_one(&flags[9], tid);
    } else if (bid == 221) {
        // ---------------- b2: sx chain (no deps) ----------------
        float* sM = lds;             // pad: sx
        float* sX = lds + 4352;      // pad: P
        float* sY = lds + 8704;      // flat
        float* sV = lds + 12800;     // ex
        for (int idx = tid; idx < 1024; idx += 256) {
            int i = idx >> 4, j4 = (idx & 15) << 2;
            *(float4*)&sM[i * LDP + j4] = *(const float4*)&sx[i * 64 + j4];
        }
        if (tid < 64) sV[tid] = ex[tid];
        __syncthreads();
        ns_invert(sM, sX, sY, NS_SX, ti, tj, tid, 1.0f);
        float aR2[4][4], aR4[4][4], aT1[4][4];
        #pragma unroll
        for (int r = 0; r < 4; ++r)
            #pragma unroll
            for (int c = 0; c < 4; ++c) { aR2[r][c] = 0.f; aR4[r][c] = 0.f; aT1[r][c] = 0.f; }
        for (int k = 0; k < 64; ++k) {
            float e = sV[k], e2 = e * e;
            float4 av = *(const float4*)&sX[k * LDP + 4 * ti];
            float4 bv = *(const float4*)&sX[k * LDP + 4 * tj];
            float avv[4] = {av.x, av.y, av.z, av.w};
            #pragma unroll
            for (int r = 0; r < 4; ++r) {
                FMA4(aR4[r], avv[r], bv);
                float ea = e * avv[r];
                FMA4(aR2[r], ea, bv);
                float e2a = e2 * avv[r];
                FMA4(aT1[r], e2a, bv);
            }
        }
        #pragma unroll
        for (int r = 0; r < 4; ++r) {
            int o = (4 * ti + r) * 64 + 4 * tj;
            float4 v2 = {aR2[r][0], aR2[r][1], aR2[r][2], aR2[r][3]};
            float4 v4 = {aR4[r][0], aR4[r][1], aR4[r][2], aR4[r][3]};
            float4 v1 = {aT1[r][0], aT1[r][1], aT1[r][2], aT1[r][3]};
            *(float4*)&ws[WS_R2 + o] = v2;
            *(float4*)&ws[WS_R4 + o] = v4;
            *(float4*)&ws[WS_T1 + o] = v1;
        }
        signal_one(&flags[9], tid);
    } else if (bid == 222) {
        // ---------------- b1': Frobenius alpha + NS(G1) -> GINV ----------
        wait_ge(&flags[8], 4, tid);
        float* sG = lds;             // pad: G1
        float* sX = lds + 4352;      // pad: NS X
        float* sY = lds + 8704;      // flat: NS tmp
        float* sV = lds + 12800;     // 128: Frobenius reduce
        for (int idx = tid; idx < 1024; idx += 256) {
            int i = idx >> 4, j4 = (idx & 15) << 2;
            *(float4*)&sG[i * LDP + j4] = *(const float4*)&ws[WS_G1 + i * 64 + j4];
        }
        __syncthreads();
        if (tid < 64) {
            float s = 0.f;
            for (int j4 = 0; j4 < 64; j4 += 4) {
                float4 v = *(const float4*)&sG[tid * LDP + j4];
                s += v.x * v.x + v.y * v.y + v.z * v.z + v.w * v.w;
            }
            sV[tid] = s;
            sV[64 + tid] = sG[tid * LDP + tid];
        }
        __syncthreads();
        float f2 = 0.f, tr = 0.f;
        for (int i = 0; i < 64; ++i) { f2 += sV[i]; tr += sV[64 + i]; }
        ns_invert(sG, sX, sY, NS_G, ti, tj, tid, tr / f2);
        for (int idx = tid; idx < 1024; idx += 256) {
            int i = idx >> 4, j4 = (idx & 15) << 2;
            *(float4*)&ws[WS_GINV + i * 64 + j4] = *(const float4*)&sX[i * LDP + j4];
        }
        signal_one(&flags[9], tid);
    } else if (bid == 223) {
        // ---------------- b3: FyAT = Fy A^T ----------------
        wait_ge(&flags[10], 216, tid);
        float* sFy = lds;            // pad
        float* sAx = lds + 4352;     // pad
        float a[4][4];
        #pragma unroll
        for (int r = 0; r < 4; ++r)
            #pragma unroll
            for (int c = 0; c < 4; ++c) a[r][c] = 0.f;
        for (int ch = 0; ch < 4; ++ch) {
            for (int idx = tid; idx < 1024; idx += 256) {
                int i = idx >> 4, m4 = (idx & 15) << 2;
                *(float4*)&sFy[i * LDP + m4] = *(const float4*)&ws[WS_FY + i * 256 + (ch << 6) + m4];
                *(float4*)&sAx[i * LDP + m4] = *(const float4*)&ws[WS_A  + i * 256 + (ch << 6) + m4];
            }
            __syncthreads();
            for (int m = 0; m < 64; m += 4) {
                float4 av[4], bv[4];
                #pragma unroll
                for (int r = 0; r < 4; ++r) av[r] = *(const float4*)&sFy[(4 * ti + r) * LDP + m];
                #pragma unroll
                for (int c = 0; c < 4; ++c) bv[c] = *(const float4*)&sAx[(4 * tj + c) * LDP + m];
                #pragma unroll
                for (int r = 0; r < 4; ++r)
                    #pragma unroll
                    for (int c = 0; c < 4; ++c)
                        a[r][c] += av[r].x * bv[c].x + av[r].y * bv[c].y
                                 + av[r].z * bv[c].z + av[r].w * bv[c].w;
            }
            __syncthreads();
        }
        #pragma unroll
        for (int r = 0; r < 4; ++r) {
            float4 v = {a[r][0], a[r][1], a[r][2], a[r][3]};
            *(float4*)&ws[WS_FYAT + (4 * ti + r) * 64 + 4 * tj] = v;
        }
        signal_one(&flags[9], tid);
    } else {
        // ---------------- k3: hybrid residual Richardson ----------------
        wait_ge(&flags[9], 4, tid);
        float* cM1   = lds;              // flat
        float* cR2   = lds + 4096;      // flat
        float* cR4   = lds + 8192;      // flat
        float* cGinv = lds + 12288;     // flat
        float* sE    = lds + 16384;     // flat (E2)
        float* sX    = lds + 20480;     // pad
        float* cC    = lds + 24832;     // pad
        float* sW    = lds + 29184;     // pad

        for (int idx = tid; idx < 1024; idx += 256) {
            int i = idx >> 4, j4 = (idx & 15) << 2;
            int o = i * 64 + j4;
            float4 g = *(const float4*)&ws[WS_G1 + o];
            float4 t = *(const float4*)&ws[WS_T1 + o];
            float4 m = {fmaf(LMBDA, t.x, g.x), fmaf(LMBDA, t.y, g.y),
                        fmaf(LMBDA, t.z, g.z), fmaf(LMBDA, t.w, g.w)};
            *(float4*)&cM1[o]   = m;
            *(float4*)&cR2[o]   = *(const float4*)&ws[WS_R2 + o];
            *(float4*)&cR4[o]   = *(const float4*)&ws[WS_R4 + o];
            *(float4*)&cGinv[o] = *(const float4*)&ws[WS_GINV + o];
            *(float4*)&cC[i * LDP + j4] = *(const float4*)&ws[WS_C + o];
        }
        float4 eyv = *(const float4*)&ey[4 * ti];
        float eyr[4] = {eyv.x, eyv.y, eyv.z, eyv.w};
        float leyr[4];
        #pragma unroll
        for (int r = 0; r < 4; ++r) leyr[r] = LMBDA * eyr[r];

        float fyr[4][4], xreg[4][4];
        #pragma unroll
        for (int r = 0; r < 4; ++r) {
            float4 v = *(const float4*)&ws[WS_FYAT + (4 * ti + r) * 64 + 4 * tj];
            fyr[r][0] = v.x; fyr[r][1] = v.y; fyr[r][2] = v.z; fyr[r][3] = v.w;
            float4 z = {0.f, 0.f, 0.f, 0.f};
            *(float4*)&sX[(4 * ti + r) * LDP + 4 * tj] = z;
            #pragma unroll
            for (int c = 0; c < 4; ++c) xreg[r][c] = 0.f;
        }
        __syncthreads();

        float E1[4][4];
        for (int it = 0; it < OUTER; ++it) {
            // grp1: Sm=X*M1, S2=X*R2, S4=X*R4 (shared A-reads)
            {
                float Sm[4][4], S2[4][4], S4[4][4];
                #pragma unroll
                for (int r = 0; r < 4; ++r)
                    #pragma unroll
                    for (int c = 0; c < 4; ++c) { Sm[r][c] = 0.f; S2[r][c] = 0.f; S4[r][c] = 0.f; }
                #pragma unroll 2
                for (int k = 0; k < 64; k += 4) {
                    float4 av[4];
                    #pragma unroll
                    for (int r = 0; r < 4; ++r)
                        av[r] = *(const float4*)&sX[(4 * ti + r) * LDP + k];
                    #pragma unroll
                    for (int q = 0; q < 4; ++q) {
                        float4 mv = *(const float4*)&cM1[(k + q) * 64 + 4 * tj];
                        float4 qv = *(const float4*)&cR2[(k + q) * 64 + 4 * tj];
                        float4 rv = *(const float4*)&cR4[(k + q) * 64 + 4 * tj];
                        float xq[4] = {av[0].x, av[1].x, av[2].x, av[3].x};
                        if (q == 1) { xq[0]=av[0].y; xq[1]=av[1].y; xq[2]=av[2].y; xq[3]=av[3].y; }
                        if (q == 2) { xq[0]=av[0].z; xq[1]=av[1].z; xq[2]=av[2].z; xq[3]=av[3].z; }
                        if (q == 3) { xq[0]=av[0].w; xq[1]=av[1].w; xq[2]=av[2].w; xq[3]=av[3].w; }
                        #pragma unroll
                        for (int r = 0; r < 4; ++r) {
                            FMA4(Sm[r], xq[r], mv);
                            FMA4(S2[r], xq[r], qv);
                            FMA4(S4[r], xq[r], rv);
                        }
                    }
                }
                #pragma unroll
                for (int r = 0; r < 4; ++r) {
                    float4 e2;
                    e2.x = LMBDA * fmaf(eyr[r], S4[r][0], -S2[r][0]);
                    e2.y = LMBDA * fmaf(eyr[r], S4[r][1], -S2[r][1]);
                    e2.z = LMBDA * fmaf(eyr[r], S4[r][2], -S2[r][2]);
                    e2.w = LMBDA * fmaf(eyr[r], S4[r][3], -S2[r][3]);
                    *(float4*)&sE[(4 * ti + r) * 64 + 4 * tj] = e2;
                    #pragma unroll
                    for (int c = 0; c < 4; ++c)
                        E1[r][c] = fmaf(-leyr[r], S2[r][c], Sm[r][c]);
                }
            }
            __syncthreads();
            // grp2: Z = C*E2 ; W = FyAT - E1 - Z
            {
                float Z[4][4];
                #pragma unroll
                for (int r = 0; r < 4; ++r)
                    #pragma unroll
                    for (int c = 0; c < 4; ++c) Z[r][c] = 0.f;
                mm64<LDP, 64>(cC, sE, ti, tj, Z);
                #pragma unroll
                for (int r = 0; r < 4; ++r) {
                    float4 w;
                    w.x = fyr[r][0] - E1[r][0] - Z[r][0];
                    w.y = fyr[r][1] - E1[r][1] - Z[r][1];
                    w.z = fyr[r][2] - E1[r][2] - Z[r][2];
                    w.w = fyr[r][3] - E1[r][3] - Z[r][3];
                    *(float4*)&sW[(4 * ti + r) * LDP + 4 * tj] = w;
                }
            }
            __syncthreads();
            // grp3: dX = W*Ginv ; X += dX
            {
                float dX[4][4];
                #pragma unroll
                for (int r = 0; r < 4; ++r)
                    #pragma unroll
                    for (int c = 0; c < 4; ++c) dX[r][c] = 0.f;
                mm64<LDP, 64>(sW, cGinv, ti, tj, dX);
                #pragma unroll
                for (int r = 0; r < 4; ++r) {
                    float4 v;
                    #pragma unroll
                    for (int c = 0; c < 4; ++c) xreg[r][c] += dX[r][c];
                    v.x = xreg[r][0]; v.y = xreg[r][1]; v.z = xreg[r][2]; v.w = xreg[r][3];
                    *(float4*)&sX[(4 * ti + r) * LDP + 4 * tj] = v;
                    if (it == OUTER - 1)
                        *(float4*)&out[(4 * ti + r) * 64 + 4 * tj] = v;
                }
            }
            if (it == OUTER - 1) break;
            __syncthreads();
        }
    }
}

extern "C" void kernel_launch(void* const* d_in, const int* in_sizes, int n_in,
                              void* d_out, int out_size, void* d_ws, size_t ws_size,
                              hipStream_t stream) {
    (void)in_sizes; (void)n_in; (void)out_size; (void)ws_size;
    const float* fx = (const float*)d_in[0];
    const float* fy = (const float*)d_in[1];
    const float* ex = (const float*)d_in[2];
    const float* ey = (const float*)d_in[3];
    const float* tx = (const float*)d_in[4];
    const float* ty = (const float*)d_in[5];
    const float* sx = (const float*)d_in[6];
    const float* sy = (const float*)d_in[7];
    float* ws = (float*)d_ws;
    float* out = (float*)d_out;

    (void)hipFuncSetAttribute((const void*)fused_fmnet,
                              hipFuncAttributeMaxDynamicSharedMemorySize, 134144);

    // zero A, Fy, G1 accumulators + the flag block
    (void)hipMemsetAsync(d_ws, 0, (WS_G1 + 4096) * sizeof(float), stream);
    (void)hipMemsetAsync((char*)d_ws + WS_FLAGS * sizeof(float), 0, 64, stream);
    fused_fmnet<<<225, 256, 134144, stream>>>(fx, fy, ex, ey, tx, ty, sx, sy, ws, out);
}